// Round 1
// baseline (347.352 us; speedup 1.0000x reference)
//
#include <hip/hip_runtime.h>

#define T_TOK 4096
#define D_DIM 1024
#define H_DIM 2048
#define NE 8
#define NA 2
#define TA (T_TOK*NA)          // 8192 token-slot pairs
#define BM 128
#define MAXTILES 72            // ceil: floor(8192/128) + 8 = 72
#define MAXPAD (MAXTILES*BM)   // 9216 padded rows

typedef __attribute__((ext_vector_type(4))) float f32x4;
typedef __attribute__((ext_vector_type(8))) short s16x8;

// ws int-area layout (int indices)
#define WS_CNT  0    // [8]
#define WS_CUR  8    // [8]
#define WS_META 16   // [2] {ntiles, total_padded}
#define WS_TEXP 18   // [<=72] tile -> expert
#define WS_PERM 256  // [MAXPAD] sorted row -> ta index (or -1 = pad)

__device__ __forceinline__ unsigned short f2bf(float f) {
  unsigned u = __builtin_bit_cast(unsigned, f);
  u += 0x7FFFu + ((u >> 16) & 1u);   // RNE (inputs finite)
  return (unsigned short)(u >> 16);
}

__device__ __forceinline__ void glds16(const unsigned short* g, unsigned short* l) {
  __builtin_amdgcn_global_load_lds(
      (const __attribute__((address_space(1))) unsigned int*)g,
      (__attribute__((address_space(3))) unsigned int*)l, 16, 0, 0);
}

// ---------------- routing ----------------
__global__ void k_count(const int* __restrict__ idx, int* __restrict__ ws) {
  int i = blockIdx.x * 256 + threadIdx.x;
  if (i < TA) atomicAdd(&ws[WS_CNT + idx[i]], 1);
}

__global__ void k_scan(int* __restrict__ ws) {
  if (threadIdx.x == 0) {
    int off = 0, ti = 0;
    for (int e = 0; e < NE; ++e) {
      ws[WS_CUR + e] = off;
      int c = ws[WS_CNT + e];
      int nt = (c + BM - 1) / BM;
      for (int k = 0; k < nt; ++k) ws[WS_TEXP + ti++] = e;
      off += nt * BM;
    }
    ws[WS_META] = ti;
    ws[WS_META + 1] = off;
  }
}

__global__ void k_place(const int* __restrict__ idx, int* __restrict__ ws) {
  int i = blockIdx.x * 256 + threadIdx.x;
  if (i < TA) {
    int e = idx[i];
    int pos = atomicAdd(&ws[WS_CUR + e], 1);
    ws[WS_PERM + pos] = i;
  }
}

// ---------------- f32 -> bf16 weight convert (n divisible by 2048) ----------------
__global__ void k_cvt(const float* __restrict__ s, unsigned short* __restrict__ d) {
  int i = (blockIdx.x * 256 + threadIdx.x) * 8;
  f32x4 a = *(const f32x4*)(s + i);
  f32x4 b = *(const f32x4*)(s + i + 4);
  s16x8 o;
  o[0] = (short)f2bf(a[0]); o[1] = (short)f2bf(a[1]);
  o[2] = (short)f2bf(a[2]); o[3] = (short)f2bf(a[3]);
  o[4] = (short)f2bf(b[0]); o[5] = (short)f2bf(b[1]);
  o[6] = (short)f2bf(b[2]); o[7] = (short)f2bf(b[3]);
  *(s16x8*)(d + i) = o;
}

// ---------------- gather x rows (permuted, bf16, zero pads) ----------------
__global__ void k_gather(const float* __restrict__ x, const int* __restrict__ ws,
                         unsigned short* __restrict__ xb) {
  int tid = blockIdx.x * 256 + threadIdx.x;   // MAXPAD*128 threads
  int r = tid >> 7;
  int c = (tid & 127) << 3;
  int ta = ws[WS_PERM + r];
  s16x8 o = {0,0,0,0,0,0,0,0};
  if (ta >= 0) {
    const float* xp = x + (size_t)(ta >> 1) * D_DIM + c;
    f32x4 a = *(const f32x4*)xp;
    f32x4 b = *(const f32x4*)(xp + 4);
    o[0] = (short)f2bf(a[0]); o[1] = (short)f2bf(a[1]);
    o[2] = (short)f2bf(a[2]); o[3] = (short)f2bf(a[3]);
    o[4] = (short)f2bf(b[0]); o[5] = (short)f2bf(b[1]);
    o[6] = (short)f2bf(b[2]); o[7] = (short)f2bf(b[3]);
  }
  *(s16x8*)(xb + (size_t)r * D_DIM + c) = o;
}

// ---------------- GEMM1: h = silu(x@Wg^T) * (x@Wu^T), per-expert tiles ----------------
// BM=128, BN=128 (per matrix), BK=64, 512 threads (8 waves, 2x4)
__global__ __launch_bounds__(512) void k_gemm1(
    const unsigned short* __restrict__ xb, const unsigned short* __restrict__ wgb,
    const unsigned short* __restrict__ wub, unsigned short* __restrict__ hb,
    const int* __restrict__ ws) {
  int mt = blockIdx.y;
  if (mt >= ws[WS_META]) return;
  int e = ws[WS_TEXP + mt];
  int nt = blockIdx.x;

  __shared__ unsigned short lA[128 * 64], lBg[128 * 64], lBu[128 * 64];

  int tid = threadIdx.x;
  int lane = tid & 63, wid = tid >> 6;
  int wm = wid & 1, wn = wid >> 1;

  int sr = tid >> 3;             // staging row (0..63 per issue)
  int sc = (tid & 7) << 3;       // staging col
  const unsigned short* gA  = xb  + ((size_t)(mt * 128 + sr)) * 1024 + sc;
  const unsigned short* gBg = wgb + ((size_t)(e * 2048 + nt * 128 + sr)) * 1024 + sc;
  const unsigned short* gBu = wub + ((size_t)(e * 2048 + nt * 128 + sr)) * 1024 + sc;

  f32x4 accg[4][2] = {};
  f32x4 accu[4][2] = {};

  int roA = (wm * 64 + (lane & 15)) * 64 + ((lane >> 4) << 3);
  int roB = (wn * 32 + (lane & 15)) * 64 + ((lane >> 4) << 3);

  for (int kt = 0; kt < 16; ++kt) {
    int k0 = kt * 64;
    glds16(gA  + k0,             &lA [tid * 8]);
    glds16(gA  + k0 + 64 * 1024, &lA [4096 + tid * 8]);
    glds16(gBg + k0,             &lBg[tid * 8]);
    glds16(gBg + k0 + 64 * 1024, &lBg[4096 + tid * 8]);
    glds16(gBu + k0,             &lBu[tid * 8]);
    glds16(gBu + k0 + 64 * 1024, &lBu[4096 + tid * 8]);
    __syncthreads();
#pragma unroll
    for (int ks = 0; ks < 2; ++ks) {
      s16x8 a[4], bg[2], bu[2];
#pragma unroll
      for (int mi = 0; mi < 4; ++mi)
        a[mi] = *(const s16x8*)&lA[roA + mi * 16 * 64 + ks * 32];
#pragma unroll
      for (int ni = 0; ni < 2; ++ni) {
        bg[ni] = *(const s16x8*)&lBg[roB + ni * 16 * 64 + ks * 32];
        bu[ni] = *(const s16x8*)&lBu[roB + ni * 16 * 64 + ks * 32];
      }
#pragma unroll
      for (int mi = 0; mi < 4; ++mi)
#pragma unroll
        for (int ni = 0; ni < 2; ++ni) {
          accg[mi][ni] = __builtin_amdgcn_mfma_f32_16x16x32_bf16(a[mi], bg[ni], accg[mi][ni], 0, 0, 0);
          accu[mi][ni] = __builtin_amdgcn_mfma_f32_16x16x32_bf16(a[mi], bu[ni], accu[mi][ni], 0, 0, 0);
        }
    }
    __syncthreads();
  }

  int mbase = mt * 128 + wm * 64 + ((lane >> 4) << 2);
  int cbase = nt * 128 + wn * 32 + (lane & 15);
#pragma unroll
  for (int mi = 0; mi < 4; ++mi)
#pragma unroll
    for (int ni = 0; ni < 2; ++ni)
#pragma unroll
      for (int r = 0; r < 4; ++r) {
        float g = accg[mi][ni][r];
        float u = accu[mi][ni][r];
        float h = (g / (1.f + __expf(-g))) * u;   // silu(g)*u
        hb[(size_t)(mbase + mi * 16 + r) * 2048 + (cbase + ni * 16)] = f2bf(h);
      }
}

// ---------------- GEMM2: out[ta] = h @ Wd[e]^T, scatter via perm ----------------
__global__ __launch_bounds__(512) void k_gemm2(
    const unsigned short* __restrict__ hb, const unsigned short* __restrict__ wdb,
    float* __restrict__ out, const int* __restrict__ ws) {
  int mt = blockIdx.y;
  if (mt >= ws[WS_META]) return;
  int e = ws[WS_TEXP + mt];
  int nt = blockIdx.x;   // 0..7

  __shared__ unsigned short lA[128 * 64], lB[128 * 64];

  int tid = threadIdx.x;
  int lane = tid & 63, wid = tid >> 6;
  int wm = wid & 1, wn = wid >> 1;

  int sr = tid >> 3;
  int sc = (tid & 7) << 3;
  const unsigned short* gA = hb  + ((size_t)(mt * 128 + sr)) * 2048 + sc;
  const unsigned short* gB = wdb + ((size_t)(e * 1024 + nt * 128 + sr)) * 2048 + sc;

  f32x4 acc[4][2] = {};

  int roA = (wm * 64 + (lane & 15)) * 64 + ((lane >> 4) << 3);
  int roB = (wn * 32 + (lane & 15)) * 64 + ((lane >> 4) << 3);

  for (int kt = 0; kt < 32; ++kt) {
    int k0 = kt * 64;
    glds16(gA + k0,             &lA[tid * 8]);
    glds16(gA + k0 + 64 * 2048, &lA[4096 + tid * 8]);
    glds16(gB + k0,             &lB[tid * 8]);
    glds16(gB + k0 + 64 * 2048, &lB[4096 + tid * 8]);
    __syncthreads();
#pragma unroll
    for (int ks = 0; ks < 2; ++ks) {
      s16x8 a[4], b[2];
#pragma unroll
      for (int mi = 0; mi < 4; ++mi)
        a[mi] = *(const s16x8*)&lA[roA + mi * 16 * 64 + ks * 32];
#pragma unroll
      for (int ni = 0; ni < 2; ++ni)
        b[ni] = *(const s16x8*)&lB[roB + ni * 16 * 64 + ks * 32];
#pragma unroll
      for (int mi = 0; mi < 4; ++mi)
#pragma unroll
        for (int ni = 0; ni < 2; ++ni)
          acc[mi][ni] = __builtin_amdgcn_mfma_f32_16x16x32_bf16(a[mi], b[ni], acc[mi][ni], 0, 0, 0);
    }
    __syncthreads();
  }

  int mbase = mt * 128 + wm * 64 + ((lane >> 4) << 2);
  int dbase = nt * 128 + wn * 32 + (lane & 15);
#pragma unroll
  for (int mi = 0; mi < 4; ++mi)
#pragma unroll
    for (int r = 0; r < 4; ++r) {
      int prow = mbase + mi * 16 + r;
      int ta = ws[WS_PERM + prow];
      if (ta >= 0) {
#pragma unroll
        for (int ni = 0; ni < 2; ++ni)
          out[(size_t)ta * 1024 + dbase + ni * 16] = acc[mi][ni][r];
      }
    }
}

extern "C" void kernel_launch(void* const* d_in, const int* in_sizes, int n_in,
                              void* d_out, int out_size, void* d_ws, size_t ws_size,
                              hipStream_t stream) {
  const float* x   = (const float*)d_in[0];
  const int*   idx = (const int*)d_in[1];
  const float* wg  = (const float*)d_in[2];
  const float* wu  = (const float*)d_in[3];
  const float* wd  = (const float*)d_in[4];
  float* out = (float*)d_out;

  int*  wsi = (int*)d_ws;
  char* wsb = (char*)d_ws;
  const size_t OFF_XB = 65536;
  const size_t OFF_WG = OFF_XB + (size_t)MAXPAD * D_DIM * 2;      // 18.9 MB xb
  const size_t OFF_WU = OFF_WG + (size_t)NE * H_DIM * D_DIM * 2;  // 33.5 MB each
  const size_t OFF_WD = OFF_WU + (size_t)NE * H_DIM * D_DIM * 2;
  const size_t OFF_HB = OFF_WD + (size_t)NE * D_DIM * H_DIM * 2;
  unsigned short* xb  = (unsigned short*)(wsb + OFF_XB);
  unsigned short* wgb = (unsigned short*)(wsb + OFF_WG);
  unsigned short* wub = (unsigned short*)(wsb + OFF_WU);
  unsigned short* wdb = (unsigned short*)(wsb + OFF_WD);
  unsigned short* hb  = (unsigned short*)(wsb + OFF_HB);

  hipMemsetAsync(wsi, 0, 96 * sizeof(int), stream);                 // cnt/cur/meta/texp
  hipMemsetAsync(wsi + WS_PERM, 0xFF, MAXPAD * sizeof(int), stream); // perm = -1

  k_count<<<TA / 256, 256, 0, stream>>>(idx, wsi);
  k_scan<<<1, 64, 0, stream>>>(wsi);
  k_place<<<TA / 256, 256, 0, stream>>>(idx, wsi);

  k_cvt<<<(NE * H_DIM * D_DIM) / (256 * 8), 256, 0, stream>>>(wg, wgb);
  k_cvt<<<(NE * H_DIM * D_DIM) / (256 * 8), 256, 0, stream>>>(wu, wub);
  k_cvt<<<(NE * D_DIM * H_DIM) / (256 * 8), 256, 0, stream>>>(wd, wdb);
  k_gather<<<(MAXPAD * (D_DIM / 8)) / 256, 256, 0, stream>>>(x, wsi, xb);

  k_gemm1<<<dim3(H_DIM / 128, MAXTILES), 512, 0, stream>>>(xb, wgb, wub, hb, wsi);
  k_gemm2<<<dim3(D_DIM / 128, MAXTILES), 512, 0, stream>>>(hb, wdb, out, wsi);
}

// Round 2
// 297.561 us; speedup vs baseline: 1.1673x; 1.1673x over previous
//
#include <hip/hip_runtime.h>

#define T_TOK 4096
#define D_DIM 1024
#define H_DIM 2048
#define NE 8
#define NA 2
#define TA (T_TOK*NA)          // 8192 token-slot pairs
#define BM 128
#define MAXTILES 72            // floor(8192/128) + 8 = 72
#define MAXPAD (MAXTILES*BM)   // 9216 padded rows

typedef __attribute__((ext_vector_type(4))) float f32x4;
typedef __attribute__((ext_vector_type(8))) short s16x8;

// ws int-area layout (int indices)
#define WS_CNT  0    // [8]
#define WS_CUR  8    // [8]
#define WS_META 16   // [2] {ntiles, total_padded}
#define WS_TEXP 18   // [<=72] tile -> expert
#define WS_PERM 256  // [MAXPAD] sorted row -> ta index (or -1 = pad)

#define WAITVM(N) asm volatile("s_waitcnt vmcnt(" #N ")" ::: "memory")
#define LGKM0()   asm volatile("s_waitcnt lgkmcnt(0)" ::: "memory")
#define BAR()     asm volatile("s_barrier" ::: "memory")

__device__ __forceinline__ unsigned short f2bf(float f) {
  unsigned u = __builtin_bit_cast(unsigned, f);
  u += 0x7FFFu + ((u >> 16) & 1u);   // RNE (inputs finite)
  return (unsigned short)(u >> 16);
}

__device__ __forceinline__ void glds16(const unsigned short* g, unsigned short* l) {
  __builtin_amdgcn_global_load_lds(
      (const __attribute__((address_space(1))) unsigned int*)g,
      (__attribute__((address_space(3))) unsigned int*)l, 16, 0, 0);
}

// ---------------- routing ----------------
__global__ void k_count(const int* __restrict__ idx, int* __restrict__ ws) {
  int i = blockIdx.x * 256 + threadIdx.x;
  if (i < TA) atomicAdd(&ws[WS_CNT + idx[i]], 1);
}

__global__ void k_scan(int* __restrict__ ws) {
  if (threadIdx.x == 0) {
    int off = 0, ti = 0;
    for (int e = 0; e < NE; ++e) {
      ws[WS_CUR + e] = off;
      int c = ws[WS_CNT + e];
      int nt = (c + BM - 1) / BM;
      for (int k = 0; k < nt; ++k) ws[WS_TEXP + ti++] = e;
      off += nt * BM;
    }
    ws[WS_META] = ti;
    ws[WS_META + 1] = off;
  }
}

__global__ void k_place(const int* __restrict__ idx, int* __restrict__ ws) {
  int i = blockIdx.x * 256 + threadIdx.x;
  if (i < TA) {
    int e = idx[i];
    int pos = atomicAdd(&ws[WS_CUR + e], 1);
    ws[WS_PERM + pos] = i;
  }
}

// ---------------- f32 -> bf16 weight convert ----------------
__global__ void k_cvt(const float* __restrict__ s, unsigned short* __restrict__ d) {
  int i = (blockIdx.x * 256 + threadIdx.x) * 8;
  f32x4 a = *(const f32x4*)(s + i);
  f32x4 b = *(const f32x4*)(s + i + 4);
  s16x8 o;
  o[0] = (short)f2bf(a[0]); o[1] = (short)f2bf(a[1]);
  o[2] = (short)f2bf(a[2]); o[3] = (short)f2bf(a[3]);
  o[4] = (short)f2bf(b[0]); o[5] = (short)f2bf(b[1]);
  o[6] = (short)f2bf(b[2]); o[7] = (short)f2bf(b[3]);
  *(s16x8*)(d + i) = o;
}

// ---------------- gather x rows (permuted, bf16, zero pads) ----------------
__global__ void k_gather(const float* __restrict__ x, const int* __restrict__ ws,
                         unsigned short* __restrict__ xb) {
  int tid = blockIdx.x * 256 + threadIdx.x;
  int r = tid >> 7;
  int c = (tid & 127) << 3;
  int ta = ws[WS_PERM + r];
  s16x8 o = {0,0,0,0,0,0,0,0};
  if (ta >= 0) {
    const float* xp = x + (size_t)(ta >> 1) * D_DIM + c;
    f32x4 a = *(const f32x4*)xp;
    f32x4 b = *(const f32x4*)(xp + 4);
    o[0] = (short)f2bf(a[0]); o[1] = (short)f2bf(a[1]);
    o[2] = (short)f2bf(a[2]); o[3] = (short)f2bf(a[3]);
    o[4] = (short)f2bf(b[0]); o[5] = (short)f2bf(b[1]);
    o[6] = (short)f2bf(b[2]); o[7] = (short)f2bf(b[3]);
  }
  *(s16x8*)(xb + (size_t)r * D_DIM + c) = o;
}

// ---------------- GEMM1: h = silu(x@Wg^T)*(x@Wu^T) ----------------
// BM=128, BN=128/matrix, BK=64, 512 thr (8 waves 2x4).
// Pipelined: 2-deep LDS dbuf, counted vmcnt(6), raw s_barrier,
// T2 source-swizzle (chunk c ^ row&7), T5 setprio around MFMA.
__global__ __launch_bounds__(512) void k_gemm1(
    const unsigned short* __restrict__ xb, const unsigned short* __restrict__ wgb,
    const unsigned short* __restrict__ wub, unsigned short* __restrict__ hb,
    const int* __restrict__ ws) {
  int mt = blockIdx.y;
  if (mt >= ws[WS_META]) return;
  int e = ws[WS_TEXP + mt];
  int nt = blockIdx.x;

  __shared__ unsigned short L[2][3 * 8192];   // per buf: A | Bg | Bu (48KB), 96KB total

  int tid = threadIdx.x;
  int lane = tid & 63, wid = tid >> 6;
  int wm = wid & 1, wn = wid >> 1;

  // staging: thread -> (row sr, 16B chunk), swizzled SOURCE chunk cs = c ^ (sr&7)
  int sr = tid >> 3;
  int cs = (tid & 7) ^ (sr & 7);
  const unsigned short* gA  = xb  + (size_t)(mt * 128 + sr) * 1024 + cs * 8;
  const unsigned short* gBg = wgb + (size_t)(e * 2048 + nt * 128 + sr) * 1024 + cs * 8;
  const unsigned short* gBu = wub + (size_t)(e * 2048 + nt * 128 + sr) * 1024 + cs * 8;

  f32x4 accg[4][2] = {};
  f32x4 accu[4][2] = {};

  int rbA = (wm * 64 + (lane & 15)) * 64;
  int rbB = (wn * 32 + (lane & 15)) * 64;
  int cg0 = lane >> 4, l7 = lane & 7;

  // prologue: stage tile 0 into buf 0
  {
    unsigned short* b = L[0];
    glds16(gA,             b + tid * 8);
    glds16(gA  + 64*1024,  b + 4096  + tid * 8);
    glds16(gBg,            b + 8192  + tid * 8);
    glds16(gBg + 64*1024,  b + 12288 + tid * 8);
    glds16(gBu,            b + 16384 + tid * 8);
    glds16(gBu + 64*1024,  b + 20480 + tid * 8);
  }

#pragma unroll 2
  for (int kt = 0; kt < 16; ++kt) {
    int kn = (kt + 1 < 16 ? kt + 1 : kt) * 64;   // last iter: harmless re-stage
    unsigned short* bn = L[(kt + 1) & 1];
    glds16(gA  + kn,            bn + tid * 8);
    glds16(gA  + kn + 64*1024,  bn + 4096  + tid * 8);
    glds16(gBg + kn,            bn + 8192  + tid * 8);
    glds16(gBg + kn + 64*1024,  bn + 12288 + tid * 8);
    glds16(gBu + kn,            bn + 16384 + tid * 8);
    glds16(gBu + kn + 64*1024,  bn + 20480 + tid * 8);
    WAITVM(6);     // wait current tile only; next tile's 6 stay in flight
    BAR();
    const unsigned short* bc = L[kt & 1];
#pragma unroll
    for (int ks = 0; ks < 2; ++ks) {
      int xo = ((ks * 4 + cg0) ^ l7) * 8;        // swizzled chunk read
      s16x8 a[4], bg[2], bu[2];
#pragma unroll
      for (int mi = 0; mi < 4; ++mi)
        a[mi] = *(const s16x8*)&bc[rbA + mi * 1024 + xo];
#pragma unroll
      for (int ni = 0; ni < 2; ++ni) {
        bg[ni] = *(const s16x8*)&bc[8192  + rbB + ni * 1024 + xo];
        bu[ni] = *(const s16x8*)&bc[16384 + rbB + ni * 1024 + xo];
      }
      __builtin_amdgcn_s_setprio(1);
#pragma unroll
      for (int mi = 0; mi < 4; ++mi)
#pragma unroll
        for (int ni = 0; ni < 2; ++ni) {
          accg[mi][ni] = __builtin_amdgcn_mfma_f32_16x16x32_bf16(a[mi], bg[ni], accg[mi][ni], 0, 0, 0);
          accu[mi][ni] = __builtin_amdgcn_mfma_f32_16x16x32_bf16(a[mi], bu[ni], accu[mi][ni], 0, 0, 0);
        }
      __builtin_amdgcn_s_setprio(0);
    }
    LGKM0();       // my ds_reads landed -> safe for others to overwrite after bar
    BAR();
  }

  int mbase = mt * 128 + wm * 64 + ((lane >> 4) << 2);
  int cbase = nt * 128 + wn * 32 + (lane & 15);
#pragma unroll
  for (int mi = 0; mi < 4; ++mi)
#pragma unroll
    for (int ni = 0; ni < 2; ++ni)
#pragma unroll
      for (int r = 0; r < 4; ++r) {
        float g = accg[mi][ni][r];
        float u = accu[mi][ni][r];
        float h = (g / (1.f + __expf(-g))) * u;
        hb[(size_t)(mbase + mi * 16 + r) * 2048 + (cbase + ni * 16)] = f2bf(h);
      }
}

// ---------------- GEMM2: out[ta] = h @ Wd[e]^T, scatter via perm ----------------
__global__ __launch_bounds__(512) void k_gemm2(
    const unsigned short* __restrict__ hb, const unsigned short* __restrict__ wdb,
    float* __restrict__ out, const int* __restrict__ ws) {
  int mt = blockIdx.y;
  if (mt >= ws[WS_META]) return;
  int e = ws[WS_TEXP + mt];
  int nt = blockIdx.x;   // 0..7

  __shared__ unsigned short L[2][2 * 8192];   // per buf: A | B (32KB), 64KB total

  int tid = threadIdx.x;
  int lane = tid & 63, wid = tid >> 6;
  int wm = wid & 1, wn = wid >> 1;

  int sr = tid >> 3;
  int cs = (tid & 7) ^ (sr & 7);
  const unsigned short* gA = hb  + (size_t)(mt * 128 + sr) * 2048 + cs * 8;
  const unsigned short* gB = wdb + (size_t)(e * 1024 + nt * 128 + sr) * 2048 + cs * 8;

  f32x4 acc[4][2] = {};

  int rbA = (wm * 64 + (lane & 15)) * 64;
  int rbB = (wn * 32 + (lane & 15)) * 64;
  int cg0 = lane >> 4, l7 = lane & 7;

  {
    unsigned short* b = L[0];
    glds16(gA,            b + tid * 8);
    glds16(gA + 64*2048,  b + 4096  + tid * 8);
    glds16(gB,            b + 8192  + tid * 8);
    glds16(gB + 64*2048,  b + 12288 + tid * 8);
  }

#pragma unroll 2
  for (int kt = 0; kt < 32; ++kt) {
    int kn = (kt + 1 < 32 ? kt + 1 : kt) * 64;
    unsigned short* bn = L[(kt + 1) & 1];
    glds16(gA + kn,           bn + tid * 8);
    glds16(gA + kn + 64*2048, bn + 4096  + tid * 8);
    glds16(gB + kn,           bn + 8192  + tid * 8);
    glds16(gB + kn + 64*2048, bn + 12288 + tid * 8);
    WAITVM(4);
    BAR();
    const unsigned short* bc = L[kt & 1];
#pragma unroll
    for (int ks = 0; ks < 2; ++ks) {
      int xo = ((ks * 4 + cg0) ^ l7) * 8;
      s16x8 a[4], b[2];
#pragma unroll
      for (int mi = 0; mi < 4; ++mi)
        a[mi] = *(const s16x8*)&bc[rbA + mi * 1024 + xo];
#pragma unroll
      for (int ni = 0; ni < 2; ++ni)
        b[ni] = *(const s16x8*)&bc[8192 + rbB + ni * 1024 + xo];
      __builtin_amdgcn_s_setprio(1);
#pragma unroll
      for (int mi = 0; mi < 4; ++mi)
#pragma unroll
        for (int ni = 0; ni < 2; ++ni)
          acc[mi][ni] = __builtin_amdgcn_mfma_f32_16x16x32_bf16(a[mi], b[ni], acc[mi][ni], 0, 0, 0);
      __builtin_amdgcn_s_setprio(0);
    }
    LGKM0();
    BAR();
  }

  int mbase = mt * 128 + wm * 64 + ((lane >> 4) << 2);
  int dbase = nt * 128 + wn * 32 + (lane & 15);
#pragma unroll
  for (int mi = 0; mi < 4; ++mi)
#pragma unroll
    for (int r = 0; r < 4; ++r) {
      int prow = mbase + mi * 16 + r;
      int ta = ws[WS_PERM + prow];
      if (ta >= 0) {
#pragma unroll
        for (int ni = 0; ni < 2; ++ni)
          out[(size_t)ta * 1024 + dbase + ni * 16] = acc[mi][ni][r];
      }
    }
}

extern "C" void kernel_launch(void* const* d_in, const int* in_sizes, int n_in,
                              void* d_out, int out_size, void* d_ws, size_t ws_size,
                              hipStream_t stream) {
  const float* x   = (const float*)d_in[0];
  const int*   idx = (const int*)d_in[1];
  const float* wg  = (const float*)d_in[2];
  const float* wu  = (const float*)d_in[3];
  const float* wd  = (const float*)d_in[4];
  float* out = (float*)d_out;

  int*  wsi = (int*)d_ws;
  char* wsb = (char*)d_ws;
  const size_t OFF_XB = 65536;
  const size_t OFF_WG = OFF_XB + (size_t)MAXPAD * D_DIM * 2;
  const size_t OFF_WU = OFF_WG + (size_t)NE * H_DIM * D_DIM * 2;
  const size_t OFF_WD = OFF_WU + (size_t)NE * H_DIM * D_DIM * 2;
  const size_t OFF_HB = OFF_WD + (size_t)NE * D_DIM * H_DIM * 2;
  unsigned short* xb  = (unsigned short*)(wsb + OFF_XB);
  unsigned short* wgb = (unsigned short*)(wsb + OFF_WG);
  unsigned short* wub = (unsigned short*)(wsb + OFF_WU);
  unsigned short* wdb = (unsigned short*)(wsb + OFF_WD);
  unsigned short* hb  = (unsigned short*)(wsb + OFF_HB);

  hipMemsetAsync(wsi, 0, 96 * sizeof(int), stream);
  hipMemsetAsync(wsi + WS_PERM, 0xFF, MAXPAD * sizeof(int), stream);

  k_count<<<TA / 256, 256, 0, stream>>>(idx, wsi);
  k_scan<<<1, 64, 0, stream>>>(wsi);
  k_place<<<TA / 256, 256, 0, stream>>>(idx, wsi);

  k_cvt<<<(NE * H_DIM * D_DIM) / (256 * 8), 256, 0, stream>>>(wg, wgb);
  k_cvt<<<(NE * H_DIM * D_DIM) / (256 * 8), 256, 0, stream>>>(wu, wub);
  k_cvt<<<(NE * D_DIM * H_DIM) / (256 * 8), 256, 0, stream>>>(wd, wdb);
  k_gather<<<(MAXPAD * (D_DIM / 8)) / 256, 256, 0, stream>>>(x, wsi, xb);

  k_gemm1<<<dim3(H_DIM / 128, MAXTILES), 512, 0, stream>>>(xb, wgb, wub, hb, wsi);
  k_gemm2<<<dim3(D_DIM / 128, MAXTILES), 512, 0, stream>>>(hb, wdb, out, wsi);
}